// Round 10
// baseline (487.877 us; speedup 1.0000x reference)
//
#include <hip/hip_runtime.h>

#define NN 64
#define KK 16
#define NW 4    // waves per batch
#define HC 16   // A-columns per wave
#define HK 4    // b-columns per wave

// Broadcast a float from a (wave-uniform) lane: v_readlane -> SGPR operand.
__device__ __forceinline__ float rlane(float v, int l) {
  return __int_as_float(__builtin_amdgcn_readlane(__float_as_int(v), l));
}

// Wave64 argmax via DPP (VALU-rate). key: u32 whose order = priority.
__device__ __forceinline__ unsigned dpp_argmax64(unsigned key) {
  unsigned t;
  t = (unsigned)__builtin_amdgcn_update_dpp(0, (int)key, 0x111, 0xf, 0xf, true);
  key = key > t ? key : t;
  t = (unsigned)__builtin_amdgcn_update_dpp(0, (int)key, 0x112, 0xf, 0xf, true);
  key = key > t ? key : t;
  t = (unsigned)__builtin_amdgcn_update_dpp(0, (int)key, 0x114, 0xf, 0xf, true);
  key = key > t ? key : t;
  t = (unsigned)__builtin_amdgcn_update_dpp(0, (int)key, 0x118, 0xf, 0xf, true);
  key = key > t ? key : t;
  t = (unsigned)__builtin_amdgcn_update_dpp(0, (int)key, 0x142, 0xf, 0xf, true);
  key = key > t ? key : t;
  t = (unsigned)__builtin_amdgcn_update_dpp(0, (int)key, 0x143, 0xf, 0xf, true);
  key = key > t ? key : t;
  return (unsigned)__builtin_amdgcn_readlane((int)key, 63);
}

// 4 waves per batch (block = 256). Lane = row. Wave w owns A-columns
// {w, w+4, ..., w+60} (mod-4 interleave) and b-columns [4w, 4w+4).
// Per-wave array state: 40 floats.
//
// THIS ROUND'S ONLY CHANGE vs the round-9 PASSING kernel (535 us):
// the A-loader is a single interleaved loop with #pragma unroll 2, capping
// in-flight float4 loads at ~4. Round-9 evidence: VGPR_Count=32 with
// occupancy 83% (~76 total regs/wave) => the 40 array floats live in AGPRs,
// paying v_accvgpr_read/write on every access (16.6k VALU instr/wave vs
// ~10k algorithmic). Hypothesis: the fully-unrolled loader's 32 concurrent
// float4 loads (~64 regs in flight) spike peak pressure to ~130, and the
// allocator responds by live-range-splitting the arrays into AGPR for
// their WHOLE lifetime (a gfx908-era policy; on gfx950's unified file it
// buys no occupancy and costs a move per access). Capping the loader kills
// the spike; arrays should stay in arch VGPRs.
//
// Step machinery is the round-5/8/9 proven pattern: owner computes pivot p
// (DPP argmax) + per-row multiplier m, publishes {m[64], p, 1/pivot} via
// LDS double-buffered by step parity, one __syncthreads(), p re-uniformed
// with readfirstlane after the divergent owner/non-owner merge.
//
// Rotation trick per wave: the owner rotates its columns left by one slot
// on its own steps, so the current column is always the owner's slot 0 and
// all register indices are compile-time constants.
__global__ void __launch_bounds__(256)
cgj_solve(const float* __restrict__ A_r, const float* __restrict__ A_i,
          const float* __restrict__ b_r, const float* __restrict__ b_i,
          float* __restrict__ out, int nbatch) {
  const int batch = blockIdx.x;
  const int w     = threadIdx.x >> 6;   // wave id: 0..3
  const int lane  = threadIdx.x & 63;   // row

  __shared__ float2 mbuf[2][64];  // per-row multiplier, dbuf by step parity
  __shared__ float4 hdr[2];       // {ip_re, ip_im, bits(p), 0}

  float Cr[HC], Ci[HC], Br[HK], Bi[HK];

  // ---- load: lane reads its full row, keeps cols == w (mod 4) ----
  // unroll 2: <=4 float4 in flight -> no register-pressure spike.
  const size_t abase = (size_t)batch * NN * NN + (size_t)lane * NN;
  const float4* pAr = reinterpret_cast<const float4*>(A_r + abase);
  const float4* pAi = reinterpret_cast<const float4*>(A_i + abase);
#pragma unroll 2
  for (int j = 0; j < HC; ++j) {
    float4 v = pAr[j];                  // cols 4j .. 4j+3; keep element w
    Cr[j] = (w & 1) ? ((w & 2) ? v.w : v.y) : ((w & 2) ? v.z : v.x);
    float4 u = pAi[j];
    Ci[j] = (w & 1) ? ((w & 2) ? u.w : u.y) : ((w & 2) ? u.z : u.x);
  }
  const size_t bbase = (size_t)batch * NN * KK + (size_t)lane * KK + (size_t)(HK * w);
  {
    float4 v = *reinterpret_cast<const float4*>(b_r + bbase);
    Br[0] = v.x; Br[1] = v.y; Br[2] = v.z; Br[3] = v.w;
    float4 u = *reinterpret_cast<const float4*>(b_i + bbase);
    Bi[0] = u.x; Bi[1] = u.y; Bi[2] = u.z; Bi[3] = u.w;
  }

  float invd_re = 0.f, invd_im = 0.f;
  int   mystep  = 0;
  bool  done    = false;

  for (int k = 0; k < NN; ++k) {
    const int owner = k & 3;
    const int buf   = k & 1;
    float m_re, m_im;
    int   p_loc;

    if (w == owner) {
      // ---- pivot: DPP argmax of |slot0|^2, lane idx in low 6 bits ----
      const float sc = Cr[0]*Cr[0] + Ci[0]*Ci[0];
      unsigned key = done ? (unsigned)lane
                          : ((__float_as_uint(sc) & ~63u) | (unsigned)lane);
      const int p = (int)(dpp_argmax64(key) & 63u);
      const float p_re = rlane(Cr[0], p);
      const float p_im = rlane(Ci[0], p);
      const float d    = p_re*p_re + p_im*p_im;
      float rd = __builtin_amdgcn_rcpf(d);
      rd = rd * (2.0f - d * rd);                  // 1 Newton step
      const float ip_re =  p_re * rd;
      const float ip_im = -p_im * rd;
      m_re = Cr[0]*ip_re - Ci[0]*ip_im;
      m_im = Cr[0]*ip_im + Ci[0]*ip_re;
      if (lane == p) {
        m_re = 0.f; m_im = 0.f;
        invd_re = ip_re; invd_im = ip_im;
        mystep = k; done = true;
      }
      mbuf[buf][lane] = float2{m_re, m_im};
      if (lane == 0)
        hdr[buf] = float4{ip_re, ip_im, __uint_as_float((unsigned)p), 0.f};
      p_loc = p;
    }
    __syncthreads();
    if (w != owner) {
      const float2 mv = mbuf[buf][lane];
      const float4 h  = hdr[buf];
      m_re = mv.x; m_im = mv.y;
      p_loc = (int)__float_as_uint(h.z);
      if (lane == p_loc) {
        invd_re = h.x; invd_im = h.y;
        mystep = k; done = true;
      }
    }
    // Re-uniform p after the divergent owner/non-owner merge.
    const int p = __builtin_amdgcn_readfirstlane(p_loc);

    // ---- A update (own columns, static indices, 4-block dead skipping) ----
    if (w == owner) {
      // live slots 0..hi; eliminate slot 0, rotate 1..hi -> 0..hi-1
      const int hi = 15 - (k >> 2);
#pragma unroll
      for (int blk = 0; blk < 4; ++blk) {
        const int j0 = (blk == 0) ? 1 : 4 * blk;
        if (hi >= j0) {
#pragma unroll
          for (int j = j0; j < 4 * (blk + 1); ++j) {
            const float sr = rlane(Cr[j], p);
            const float si = rlane(Ci[j], p);
            Cr[j-1] = __builtin_fmaf(-m_re, sr, __builtin_fmaf( m_im, si, Cr[j]));
            Ci[j-1] = __builtin_fmaf(-m_im, sr, __builtin_fmaf(-m_re, si, Ci[j]));
          }
        }
      }
    } else {
      const int e  = (k > w) ? ((k - w + 3) >> 2) : 0;
      const int hi = 15 - e;                      // update slots 0..hi in place
#pragma unroll
      for (int blk = 0; blk < 4; ++blk) {
        if (hi >= 4 * blk) {
#pragma unroll
          for (int j = 4 * blk; j < 4 * (blk + 1); ++j) {
            const float sr = rlane(Cr[j], p);
            const float si = rlane(Ci[j], p);
            Cr[j] = __builtin_fmaf(-m_re, sr, __builtin_fmaf( m_im, si, Cr[j]));
            Ci[j] = __builtin_fmaf(-m_im, sr, __builtin_fmaf(-m_re, si, Ci[j]));
          }
        }
      }
    }

    // ---- b update (own 4 columns, all waves) ----
#pragma unroll
    for (int c = 0; c < HK; ++c) {
      const float sr = rlane(Br[c], p);
      const float si = rlane(Bi[c], p);
      Br[c] = __builtin_fmaf(-m_re, sr, __builtin_fmaf( m_im, si, Br[c]));
      Bi[c] = __builtin_fmaf(-m_im, sr, __builtin_fmaf(-m_re, si, Bi[c]));
    }
  }

  // ---- x[mystep][c] = b[c] * invd ; lane writes its row, own 4 columns ----
  float xr[HK], xi[HK];
#pragma unroll
  for (int c = 0; c < HK; ++c) {
    xr[c] = Br[c]*invd_re - Bi[c]*invd_im;
    xi[c] = Br[c]*invd_im + Bi[c]*invd_re;
  }
  const size_t obase = (size_t)batch * NN * KK + (size_t)mystep * KK + (size_t)(HK * w);
  float* o_r = out + obase;
  float* o_i = out + (size_t)nbatch * NN * KK + obase;
  {
    float4 v; v.x = xr[0]; v.y = xr[1]; v.z = xr[2]; v.w = xr[3];
    *reinterpret_cast<float4*>(o_r) = v;
    float4 u; u.x = xi[0]; u.y = xi[1]; u.z = xi[2]; u.w = xi[3];
    *reinterpret_cast<float4*>(o_i) = u;
  }
}

extern "C" void kernel_launch(void* const* d_in, const int* in_sizes, int n_in,
                              void* d_out, int out_size, void* d_ws, size_t ws_size,
                              hipStream_t stream) {
  const float* A_r = (const float*)d_in[0];
  const float* A_i = (const float*)d_in[1];
  const float* b_r = (const float*)d_in[2];
  const float* b_i = (const float*)d_in[3];
  float* out = (float*)d_out;
  const int nbatch = in_sizes[0] / (NN * NN);  // 8192
  cgj_solve<<<nbatch, 256, 0, stream>>>(A_r, A_i, b_r, b_i, out, nbatch);
}

// Round 11
// 484.874 us; speedup vs baseline: 1.0062x; 1.0062x over previous
//
#include <hip/hip_runtime.h>

#define NN 64
#define KK 16
#define NW 4    // waves per batch
#define HC 16   // A-columns per wave
#define HK 4    // b-columns per wave

// Broadcast a float from a (wave-uniform) lane: v_readlane -> SGPR operand.
__device__ __forceinline__ float rlane(float v, int l) {
  return __int_as_float(__builtin_amdgcn_readlane(__float_as_int(v), l));
}

// Wave64 argmax via DPP (VALU-rate). key: u32 whose order = priority.
__device__ __forceinline__ unsigned dpp_argmax64(unsigned key) {
  unsigned t;
  t = (unsigned)__builtin_amdgcn_update_dpp(0, (int)key, 0x111, 0xf, 0xf, true);
  key = key > t ? key : t;
  t = (unsigned)__builtin_amdgcn_update_dpp(0, (int)key, 0x112, 0xf, 0xf, true);
  key = key > t ? key : t;
  t = (unsigned)__builtin_amdgcn_update_dpp(0, (int)key, 0x114, 0xf, 0xf, true);
  key = key > t ? key : t;
  t = (unsigned)__builtin_amdgcn_update_dpp(0, (int)key, 0x118, 0xf, 0xf, true);
  key = key > t ? key : t;
  t = (unsigned)__builtin_amdgcn_update_dpp(0, (int)key, 0x142, 0xf, 0xf, true);
  key = key > t ? key : t;
  t = (unsigned)__builtin_amdgcn_update_dpp(0, (int)key, 0x143, 0xf, 0xf, true);
  key = key > t ? key : t;
  return (unsigned)__builtin_amdgcn_readlane((int)key, 63);
}

// 4 waves per batch (block = 256). Lane = row. Wave w owns A-columns
// {w, w+4, ..., w+60} (mod-4 interleave) and b-columns [4w, 4w+4).
// Per-wave array state: 40 floats (~65-75 regs total demand).
//
// THIS ROUND'S ONLY CHANGE vs the round-9/10 PASSING kernel (535 us):
// amdgpu_waves_per_eu(6,6). Ten-round synthesis: with DEFAULT attributes the
// scheduler targets ~7-8 waves/EU => ~64-reg budget; the ~72-reg demand
// overflows and the RA routes the arrays through the spill-to-AGPR path
// (VGPR_Count=32 arch + ~40 AGPR), paying v_accvgpr_read/write on every
// array access (16.6k VALU instr/wave measured vs ~6k algorithmic). R7
// proved the occupancy target is the knob: waves_per_eu(1,1) made the
// allocator use 132 ARCH VGPRs (no 32-cap) but capped occupancy at 1.
// (6,6) pins the target at the natural fit: budget 512/6 -> ~80 regs, the
// ~72-reg demand fits in pure arch VGPRs (no AGPR split, no scratch) at
// 6/8 waves per SIMD -- ample for an issue-bound kernel.
//
// Step machinery is the round-5/8/9 proven pattern: owner computes pivot p
// (DPP argmax) + per-row multiplier m, publishes {m[64], p, 1/pivot} via
// LDS double-buffered by step parity, one __syncthreads(), p re-uniformed
// with readfirstlane after the divergent owner/non-owner merge.
//
// Rotation trick per wave: the owner rotates its columns left by one slot
// on its own steps, so the current column is always the owner's slot 0 and
// all register indices are compile-time constants.
__global__ void __launch_bounds__(256)
__attribute__((amdgpu_waves_per_eu(6, 6)))
cgj_solve(const float* __restrict__ A_r, const float* __restrict__ A_i,
          const float* __restrict__ b_r, const float* __restrict__ b_i,
          float* __restrict__ out, int nbatch) {
  const int batch = blockIdx.x;
  const int w     = threadIdx.x >> 6;   // wave id: 0..3
  const int lane  = threadIdx.x & 63;   // row

  __shared__ float2 mbuf[2][64];  // per-row multiplier, dbuf by step parity
  __shared__ float4 hdr[2];       // {ip_re, ip_im, bits(p), 0}

  float Cr[HC], Ci[HC], Br[HK], Bi[HK];

  // ---- load: lane reads its full row, keeps cols == w (mod 4) ----
  // unroll 2: <=4 float4 in flight -> no register-pressure spike.
  const size_t abase = (size_t)batch * NN * NN + (size_t)lane * NN;
  const float4* pAr = reinterpret_cast<const float4*>(A_r + abase);
  const float4* pAi = reinterpret_cast<const float4*>(A_i + abase);
#pragma unroll 2
  for (int j = 0; j < HC; ++j) {
    float4 v = pAr[j];                  // cols 4j .. 4j+3; keep element w
    Cr[j] = (w & 1) ? ((w & 2) ? v.w : v.y) : ((w & 2) ? v.z : v.x);
    float4 u = pAi[j];
    Ci[j] = (w & 1) ? ((w & 2) ? u.w : u.y) : ((w & 2) ? u.z : u.x);
  }
  const size_t bbase = (size_t)batch * NN * KK + (size_t)lane * KK + (size_t)(HK * w);
  {
    float4 v = *reinterpret_cast<const float4*>(b_r + bbase);
    Br[0] = v.x; Br[1] = v.y; Br[2] = v.z; Br[3] = v.w;
    float4 u = *reinterpret_cast<const float4*>(b_i + bbase);
    Bi[0] = u.x; Bi[1] = u.y; Bi[2] = u.z; Bi[3] = u.w;
  }

  float invd_re = 0.f, invd_im = 0.f;
  int   mystep  = 0;
  bool  done    = false;

  for (int k = 0; k < NN; ++k) {
    const int owner = k & 3;
    const int buf   = k & 1;
    float m_re, m_im;
    int   p_loc;

    if (w == owner) {
      // ---- pivot: DPP argmax of |slot0|^2, lane idx in low 6 bits ----
      const float sc = Cr[0]*Cr[0] + Ci[0]*Ci[0];
      unsigned key = done ? (unsigned)lane
                          : ((__float_as_uint(sc) & ~63u) | (unsigned)lane);
      const int p = (int)(dpp_argmax64(key) & 63u);
      const float p_re = rlane(Cr[0], p);
      const float p_im = rlane(Ci[0], p);
      const float d    = p_re*p_re + p_im*p_im;
      float rd = __builtin_amdgcn_rcpf(d);
      rd = rd * (2.0f - d * rd);                  // 1 Newton step
      const float ip_re =  p_re * rd;
      const float ip_im = -p_im * rd;
      m_re = Cr[0]*ip_re - Ci[0]*ip_im;
      m_im = Cr[0]*ip_im + Ci[0]*ip_re;
      if (lane == p) {
        m_re = 0.f; m_im = 0.f;
        invd_re = ip_re; invd_im = ip_im;
        mystep = k; done = true;
      }
      mbuf[buf][lane] = float2{m_re, m_im};
      if (lane == 0)
        hdr[buf] = float4{ip_re, ip_im, __uint_as_float((unsigned)p), 0.f};
      p_loc = p;
    }
    __syncthreads();
    if (w != owner) {
      const float2 mv = mbuf[buf][lane];
      const float4 h  = hdr[buf];
      m_re = mv.x; m_im = mv.y;
      p_loc = (int)__float_as_uint(h.z);
      if (lane == p_loc) {
        invd_re = h.x; invd_im = h.y;
        mystep = k; done = true;
      }
    }
    // Re-uniform p after the divergent owner/non-owner merge.
    const int p = __builtin_amdgcn_readfirstlane(p_loc);

    // ---- A update (own columns, static indices, 4-block dead skipping) ----
    if (w == owner) {
      // live slots 0..hi; eliminate slot 0, rotate 1..hi -> 0..hi-1
      const int hi = 15 - (k >> 2);
#pragma unroll
      for (int blk = 0; blk < 4; ++blk) {
        const int j0 = (blk == 0) ? 1 : 4 * blk;
        if (hi >= j0) {
#pragma unroll
          for (int j = j0; j < 4 * (blk + 1); ++j) {
            const float sr = rlane(Cr[j], p);
            const float si = rlane(Ci[j], p);
            Cr[j-1] = __builtin_fmaf(-m_re, sr, __builtin_fmaf( m_im, si, Cr[j]));
            Ci[j-1] = __builtin_fmaf(-m_im, sr, __builtin_fmaf(-m_re, si, Ci[j]));
          }
        }
      }
    } else {
      const int e  = (k > w) ? ((k - w + 3) >> 2) : 0;
      const int hi = 15 - e;                      // update slots 0..hi in place
#pragma unroll
      for (int blk = 0; blk < 4; ++blk) {
        if (hi >= 4 * blk) {
#pragma unroll
          for (int j = 4 * blk; j < 4 * (blk + 1); ++j) {
            const float sr = rlane(Cr[j], p);
            const float si = rlane(Ci[j], p);
            Cr[j] = __builtin_fmaf(-m_re, sr, __builtin_fmaf( m_im, si, Cr[j]));
            Ci[j] = __builtin_fmaf(-m_im, sr, __builtin_fmaf(-m_re, si, Ci[j]));
          }
        }
      }
    }

    // ---- b update (own 4 columns, all waves) ----
#pragma unroll
    for (int c = 0; c < HK; ++c) {
      const float sr = rlane(Br[c], p);
      const float si = rlane(Bi[c], p);
      Br[c] = __builtin_fmaf(-m_re, sr, __builtin_fmaf( m_im, si, Br[c]));
      Bi[c] = __builtin_fmaf(-m_im, sr, __builtin_fmaf(-m_re, si, Bi[c]));
    }
  }

  // ---- x[mystep][c] = b[c] * invd ; lane writes its row, own 4 columns ----
  float xr[HK], xi[HK];
#pragma unroll
  for (int c = 0; c < HK; ++c) {
    xr[c] = Br[c]*invd_re - Bi[c]*invd_im;
    xi[c] = Br[c]*invd_im + Bi[c]*invd_re;
  }
  const size_t obase = (size_t)batch * NN * KK + (size_t)mystep * KK + (size_t)(HK * w);
  float* o_r = out + obase;
  float* o_i = out + (size_t)nbatch * NN * KK + obase;
  {
    float4 v; v.x = xr[0]; v.y = xr[1]; v.z = xr[2]; v.w = xr[3];
    *reinterpret_cast<float4*>(o_r) = v;
    float4 u; u.x = xi[0]; u.y = xi[1]; u.z = xi[2]; u.w = xi[3];
    *reinterpret_cast<float4*>(o_i) = u;
  }
}

extern "C" void kernel_launch(void* const* d_in, const int* in_sizes, int n_in,
                              void* d_out, int out_size, void* d_ws, size_t ws_size,
                              hipStream_t stream) {
  const float* A_r = (const float*)d_in[0];
  const float* A_i = (const float*)d_in[1];
  const float* b_r = (const float*)d_in[2];
  const float* b_i = (const float*)d_in[3];
  float* out = (float*)d_out;
  const int nbatch = in_sizes[0] / (NN * NN);  // 8192
  cgj_solve<<<nbatch, 256, 0, stream>>>(A_r, A_i, b_r, b_i, out, nbatch);
}